// Round 7
// baseline (598.780 us; speedup 1.0000x reference)
//
#include <hip/hip_runtime.h>

typedef unsigned short u16;
typedef __attribute__((ext_vector_type(8))) short bf8_t;   // 8 bf16 in 4 VGPRs
typedef __attribute__((ext_vector_type(4))) float f4_t;

constexpr int NN   = 50000;
constexpr int NE   = 800000;
constexpr int TBLN = 2048;
constexpr int MB   = (NN + 31) / 32;  // 1563 ip blocks
constexpr int FB   = NE / 256;        // 3125 fill blocks

// ---------- helpers ----------
__device__ __forceinline__ float bf(const u16* p, int i) {
  return __uint_as_float(((unsigned)p[i]) << 16);
}
__device__ __forceinline__ u16 f2b(float f) {
  unsigned u = __float_as_uint(f);
  unsigned r = u + 0x7fffu + ((u >> 16) & 1u);  // RNE
  return (u16)(r >> 16);
}
__device__ __forceinline__ short f2bs(float f) {
  unsigned u = __float_as_uint(f);
  unsigned r = u + 0x7fffu + ((u >> 16) & 1u);
  return (short)(r >> 16);
}
__device__ __forceinline__ u16 f2h(float f) {
  _Float16 h = (_Float16)f;
  return __builtin_bit_cast(unsigned short, h);
}
__device__ __forceinline__ float h2f(u16 v) {
  _Float16 h = __builtin_bit_cast(_Float16, v);
  return (float)h;
}
__device__ __forceinline__ unsigned packh(float a, float b) {
  return (unsigned)f2h(a) | ((unsigned)f2h(b) << 16);
}
__device__ __forceinline__ float blo(unsigned u) { return __uint_as_float(u << 16); }
__device__ __forceinline__ float bhi(unsigned u) { return __uint_as_float(u & 0xffff0000u); }
__device__ __forceinline__ float wred64(float v) {
#pragma unroll
  for (int o = 32; o; o >>= 1) v += __shfl_xor(v, o);
  return v;
}
__device__ __forceinline__ bf8_t ldv(const u16* p) { return *(const bf8_t*)p; }
__device__ __forceinline__ bf8_t ldcvt(const float* p) {
  const float4 a = *(const float4*)p;
  const float4 b = *(const float4*)(p + 4);
  bf8_t r;
  r[0] = f2bs(a.x); r[1] = f2bs(a.y); r[2] = f2bs(a.z); r[3] = f2bs(a.w);
  r[4] = f2bs(b.x); r[5] = f2bs(b.y); r[6] = f2bs(b.z); r[7] = f2bs(b.w);
  return r;
}
__device__ __forceinline__ f4_t mfma16(bf8_t a, bf8_t b, f4_t c) {
  return __builtin_amdgcn_mfma_f32_16x16x32_bf16(a, b, c, 0, 0, 0);
}
__device__ __forceinline__ void acc8(float* a, uint4 r, float w) {
  a[0] += w * blo(r.x); a[1] += w * bhi(r.x);
  a[2] += w * blo(r.y); a[3] += w * bhi(r.y);
  a[4] += w * blo(r.z); a[5] += w * bhi(r.z);
  a[6] += w * blo(r.w); a[7] += w * bhi(r.w);
}
__device__ __forceinline__ void unp8(uint4 r, float* o) {
  o[0] = blo(r.x); o[1] = bhi(r.x); o[2] = blo(r.y); o[3] = bhi(r.y);
  o[4] = blo(r.z); o[5] = bhi(r.z); o[6] = blo(r.w); o[7] = bhi(r.w);
}

// ---------- prep: build_V + weight transposes + deg histogram, one launch ----------
__global__ __launch_bounds__(256) void prep_k(
    const float* __restrict__ ew1, const float* __restrict__ ate1,
    const float* __restrict__ ew2, const float* __restrict__ ate2,
    float* __restrict__ V,
    const float* __restrict__ w1, const float* __restrict__ w2,
    const float* __restrict__ gw1, const float* __restrict__ gw2,
    u16* __restrict__ w1t, u16* __restrict__ w2t,
    u16* __restrict__ g1wt, u16* __restrict__ g2wt,
    const int* __restrict__ dstv, int* __restrict__ deg) {
  const int bid = blockIdx.x, t = threadIdx.x;
  if (bid == 0) {
#pragma unroll
    for (int rep = 0; rep < 2; ++rep) {
      int idx = t + rep * 256;
      int k = idx >> 2, hd = idx & 3;
      float s1 = 0.f, s2 = 0.f;
      for (int c = 0; c < 32; ++c) {
        s1 += ew1[k * 128 + hd * 32 + c] * ate1[hd * 32 + c];
        s2 += ew2[k * 128 + hd * 32 + c] * ate2[hd * 32 + c];
      }
      V[k * 8 + hd] = s1;
      V[k * 8 + 4 + hd] = s2;
    }
  } else if (bid <= 384) {
    int idx = (bid - 1) * 256 + t;
    if (idx < 32768) {
      int r = idx >> 8, c = idx & 255;
      w1t[c * 128 + r] = f2b(w1[idx]);
    } else if (idx < 65536) {
      int k = idx - 32768;
      int r = k >> 7, c = k & 127;
      w2t[c * 256 + r] = f2b(w2[k]);
    } else if (idx < 81920) {
      int k = idx - 65536;
      int r = k >> 7, c = k & 127;
      g1wt[c * 128 + r] = f2b(gw1[k]);
    } else {
      int k = idx - 81920;
      int r = k >> 7, c = k & 127;
      g2wt[c * 128 + r] = f2b(gw2[k]);
    }
  } else {
    int e = (bid - 385) * 256 + t;
    if (e < NE) atomicAdd(&deg[dstv[e]], 1);
  }
}

// ---------- tabulate a_edge(t) ----------
__global__ __launch_bounds__(128) void build_table(
    const float* __restrict__ taw1, const float* __restrict__ tab1,
    const float* __restrict__ talnw, const float* __restrict__ talnb,
    const float* __restrict__ taw2, const float* __restrict__ tab2,
    const float* __restrict__ V, float* __restrict__ tbl) {
  const int j = threadIdx.x;
  const int wv = j >> 6, ln = j & 63;
  const float t = (float)blockIdx.x / (float)(TBLN - 1);
  __shared__ float part[4];
  __shared__ float ush[128];
  __shared__ float pacc[16];
  float v = t * taw1[j] + tab1[j];
  float s = wred64(v), sq = wred64(v * v);
  if (ln == 0) { part[wv * 2] = s; part[wv * 2 + 1] = sq; }
  __syncthreads();
  float S = part[0] + part[2], SQ = part[1] + part[3];
  float mu = S * (1.f / 128.f);
  float var = SQ * (1.f / 128.f) - mu * mu;
  float rstd = rsqrtf(var + 1e-5f);
  float u = fmaxf((v - mu) * rstd * talnw[j] + talnb[j], 0.f);
  ush[j] = u;
  __syncthreads();
  float acc = 0.f;
  for (int k = 0; k < 128; ++k) acc += ush[k] * taw2[k * 128 + j];
  float w = tanhf(acc + tab2[j]);
  w = fminf(fmaxf(w, -3.f), 3.f);
#pragma unroll
  for (int p = 0; p < 8; ++p) {
    float z = wred64(w * V[j * 8 + p]);
    if (ln == 0) pacc[wv * 8 + p] = z;
  }
  __syncthreads();
  if (j < 8) tbl[blockIdx.x * 8 + j] = pacc[j] + pacc[8 + j];
}

// ---------- scans ----------
__global__ __launch_bounds__(512) void scan1(const int* __restrict__ deg,
                                             int* __restrict__ indptr,
                                             int* __restrict__ blks) {
  const int t = threadIdx.x;
  const int i = blockIdx.x * 512 + t;
  int v = (i < NN) ? deg[i] : 0;
  const int lane = t & 63, wv = t >> 6;
  int x = v;
#pragma unroll
  for (int o = 1; o < 64; o <<= 1) {
    int y = __shfl_up(x, o);
    if (lane >= o) x += y;
  }
  __shared__ int ws[8];
  if (lane == 63) ws[wv] = x;
  __syncthreads();
  if (t < 8) {
    int y = ws[t];
#pragma unroll
    for (int o = 1; o < 8; o <<= 1) {
      int z = __shfl_up(y, o);
      if (t >= o) y += z;
    }
    ws[t] = y;
  }
  __syncthreads();
  int excl = wv ? ws[wv - 1] : 0;
  x += excl;
  if (i < NN) indptr[i + 1] = x;
  if (t == 511) blks[blockIdx.x] = x;
}
__global__ void scan2(int* __restrict__ blks, int nb) {
  const int t = threadIdx.x;
  int v = (t < nb) ? blks[t] : 0;
  const int lane = t & 63, wv = t >> 6;
  int x = v;
#pragma unroll
  for (int o = 1; o < 64; o <<= 1) {
    int y = __shfl_up(x, o);
    if (lane >= o) x += y;
  }
  __shared__ int ws[2];
  if (lane == 63) ws[wv] = x;
  __syncthreads();
  if (wv == 1) x += ws[0];
  if (t < nb) blks[t] = x - v;
}
__global__ __launch_bounds__(512) void scan3(int* __restrict__ indptr,
                                             const int* __restrict__ blks) {
  const int i = blockIdx.x * 512 + threadIdx.x;
  if (i < NN) indptr[i + 1] += blks[blockIdx.x];
  if (i == 0) indptr[0] = 0;
}

// ---------- fused: CSR fill (latency) + input-projection MFMA (compute) ----------
__device__ void fill_body(int fb, const int* __restrict__ srcv,
                          const int* __restrict__ dstv,
                          const float* __restrict__ etime,
                          const float* __restrict__ tbl,
                          const int* __restrict__ indptr, int* __restrict__ cursor,
                          u16* __restrict__ recs) {
  const int e = fb * 256 + threadIdx.x;
  if (e >= NE) return;
  int d = dstv[e];
  int p = atomicAdd(&cursor[d], 1);
  int pos = indptr[d] + p;
  float t = etime[e];
  t = fminf(fmaxf(t, 0.f), 1.f);
  float fpos = t * (float)(TBLN - 1);
  int i0 = (int)fpos;
  if (i0 > TBLN - 2) i0 = TBLN - 2;
  float fr = fpos - (float)i0;
  const float4* r = (const float4*)(tbl + i0 * 8);
  float4 a0 = r[0], a1 = r[1], b0 = r[2], b1 = r[3];
  float4 o1, o2;
  o1.x = a0.x + fr * (b0.x - a0.x); o1.y = a0.y + fr * (b0.y - a0.y);
  o1.z = a0.z + fr * (b0.z - a0.z); o1.w = a0.w + fr * (b0.w - a0.w);
  o2.x = a1.x + fr * (b1.x - a1.x); o2.y = a1.y + fr * (b1.y - a1.y);
  o2.z = a1.z + fr * (b1.z - a1.z); o2.w = a1.w + fr * (b1.w - a1.w);
  u16* rp = recs + (size_t)pos * 16;
  uint4 w;
  w.x = (unsigned)srcv[e];
  w.y = packh(o1.x, o1.y);
  w.z = packh(o1.z, o1.w);
  w.w = packh(o2.x, o2.y);
  *(uint4*)rp = w;
  *(unsigned*)(rp + 8) = packh(o2.z, o2.w);
}

__device__ void ip_body(int ipb, char* smem,
                        const float* __restrict__ x, const u16* __restrict__ w1t,
                        const float* __restrict__ b1, const float* __restrict__ ln1w,
                        const float* __restrict__ ln1b, const u16* __restrict__ w2t,
                        const float* __restrict__ b2, const float* __restrict__ pnw,
                        const float* __restrict__ pnb, u16* __restrict__ h16) {
  float* h1f = (float*)smem;              // [32][260] fp32
  u16* h1n = (u16*)(smem + 33280);        // [32][264] bf16
  u16* h2n = h1n;

  const int t = threadIdx.x;
  const int w = t >> 6, lane = t & 63, q = lane >> 4, l15 = lane & 15;
  const int rowbase = ipb * 32;

  f4_t acc[2][4];
#pragma unroll
  for (int mt = 0; mt < 2; ++mt)
#pragma unroll
    for (int nt = 0; nt < 4; ++nt) acc[mt][nt] = (f4_t){0.f, 0.f, 0.f, 0.f};
#pragma unroll
  for (int kst = 0; kst < 4; ++kst) {
    int k0 = kst * 32 + q * 8;
    int r0 = rowbase + l15;      if (r0 > NN - 1) r0 = NN - 1;
    int r1 = rowbase + 16 + l15; if (r1 > NN - 1) r1 = NN - 1;
    bf8_t a0 = ldcvt(x + r0 * 128 + k0);
    bf8_t a1 = ldcvt(x + r1 * 128 + k0);
#pragma unroll
    for (int nt = 0; nt < 4; ++nt) {
      int n = w * 64 + nt * 16 + l15;
      bf8_t b = ldv(w1t + n * 128 + k0);
      acc[0][nt] = mfma16(a0, b, acc[0][nt]);
      acc[1][nt] = mfma16(a1, b, acc[1][nt]);
    }
  }
#pragma unroll
  for (int mt = 0; mt < 2; ++mt)
#pragma unroll
    for (int nt = 0; nt < 4; ++nt) {
      int col = w * 64 + nt * 16 + l15;
      float bb = b1[col];
#pragma unroll
      for (int r = 0; r < 4; ++r) {
        int row = mt * 16 + q * 4 + r;
        h1f[row * 260 + col] = fmaxf(acc[mt][nt][r] + bb, 0.f);
      }
    }
  __syncthreads();
  {
    const int row = t >> 3, sub = t & 7;
    const float* rp = h1f + row * 260;
    float sum = 0.f, sq = 0.f;
#pragma unroll
    for (int i = 0; i < 32; ++i) {
      float v = rp[sub + 8 * i];
      sum += v; sq += v * v;
    }
#pragma unroll
    for (int o = 1; o < 8; o <<= 1) { sum += __shfl_xor(sum, o); sq += __shfl_xor(sq, o); }
    float mu = sum * (1.f / 256.f);
    float var = sq * (1.f / 256.f) - mu * mu;
    float rstd = rsqrtf(var + 1e-5f);
#pragma unroll
    for (int i = 0; i < 32; ++i) {
      int c = sub + 8 * i;
      float v = (rp[c] - mu) * rstd * ln1w[c] + ln1b[c];
      h1n[row * 264 + c] = f2b(v);
    }
  }
  __syncthreads();
  f4_t acc2[2][2];
#pragma unroll
  for (int mt = 0; mt < 2; ++mt)
#pragma unroll
    for (int nt = 0; nt < 2; ++nt) acc2[mt][nt] = (f4_t){0.f, 0.f, 0.f, 0.f};
#pragma unroll
  for (int kst = 0; kst < 8; ++kst) {
    int k0 = kst * 32 + q * 8;
    bf8_t a0 = ldv(h1n + (l15) * 264 + k0);
    bf8_t a1 = ldv(h1n + (16 + l15) * 264 + k0);
#pragma unroll
    for (int nt = 0; nt < 2; ++nt) {
      int n = w * 32 + nt * 16 + l15;
      bf8_t b = ldv(w2t + n * 256 + k0);
      acc2[0][nt] = mfma16(a0, b, acc2[0][nt]);
      acc2[1][nt] = mfma16(a1, b, acc2[1][nt]);
    }
  }
  __syncthreads();
#pragma unroll
  for (int mt = 0; mt < 2; ++mt)
#pragma unroll
    for (int nt = 0; nt < 2; ++nt) {
      int col = w * 32 + nt * 16 + l15;
      float bb = b2[col];
#pragma unroll
      for (int r = 0; r < 4; ++r) {
        int row = mt * 16 + q * 4 + r;
        h1f[row * 132 + col] = acc2[mt][nt][r] + bb;
      }
    }
  __syncthreads();
  {
    const int row = t >> 3, sub = t & 7;
    const float* rp = h1f + row * 132;
    float sum = 0.f, sq = 0.f;
#pragma unroll
    for (int i = 0; i < 16; ++i) {
      float v = rp[sub + 8 * i];
      sum += v; sq += v * v;
    }
#pragma unroll
    for (int o = 1; o < 8; o <<= 1) { sum += __shfl_xor(sum, o); sq += __shfl_xor(sq, o); }
    float mu = sum * (1.f / 128.f);
    float var = sq * (1.f / 128.f) - mu * mu;
    float rstd = rsqrtf(var + 1e-5f);
#pragma unroll
    for (int i = 0; i < 16; ++i) {
      int c = sub + 8 * i;
      float v = (rp[c] - mu) * rstd * pnw[c] + pnb[c];
      v = fminf(fmaxf(v, 0.f), 10.f);
      h2n[row * 128 + c] = f2b(v);
    }
  }
  __syncthreads();
  {
    const int row = t >> 3, cb = (t & 7) * 16;
    int rg = rowbase + row;
    if (rg < NN) {
      uint4 v0 = *(const uint4*)(h2n + row * 128 + cb);
      uint4 v1 = *(const uint4*)(h2n + row * 128 + cb + 8);
      *(uint4*)(h16 + rg * 128 + cb) = v0;
      *(uint4*)(h16 + rg * 128 + cb + 8) = v1;
    }
  }
}

__global__ __launch_bounds__(256) void fillip_k(
    const int* srcv, const int* dstv, const float* etime, const float* tbl,
    const int* indptr, int* cursor, u16* recs,
    const float* x, const u16* w1t, const float* b1, const float* ln1w,
    const float* ln1b, const u16* w2t, const float* b2, const float* pnw,
    const float* pnb, u16* h16) {
  __shared__ char smem[50176];
  const int bid = blockIdx.x;
  if (bid % 3 == 0) {
    ip_body(bid / 3, smem, x, w1t, b1, ln1w, ln1b, w2t, b2, pnw, pnb, h16);
  } else {
    fill_body(bid - bid / 3 - 1, srcv, dstv, etime, tbl, indptr, cursor, recs);
  }
}

// ---------- MFMA node projection + attention logits ----------
__global__ __launch_bounds__(256) void hp_mfma(
    const u16* __restrict__ feat16, const u16* __restrict__ wt,
    const float* __restrict__ attsrc, const float* __restrict__ attdst,
    u16* __restrict__ hp16, float* __restrict__ asrc, float* __restrict__ adst) {
  const int t = threadIdx.x;
  const int w = t >> 6, lane = t & 63, q = lane >> 4, l15 = lane & 15;
  const int rowbase = blockIdx.x * 32;
  f4_t acc[2][2];
#pragma unroll
  for (int mt = 0; mt < 2; ++mt)
#pragma unroll
    for (int nt = 0; nt < 2; ++nt) acc[mt][nt] = (f4_t){0.f, 0.f, 0.f, 0.f};
#pragma unroll
  for (int kst = 0; kst < 4; ++kst) {
    int k0 = kst * 32 + q * 8;
    int r0 = rowbase + l15;      if (r0 > NN - 1) r0 = NN - 1;
    int r1 = rowbase + 16 + l15; if (r1 > NN - 1) r1 = NN - 1;
    bf8_t a0 = ldv(feat16 + r0 * 128 + k0);
    bf8_t a1 = ldv(feat16 + r1 * 128 + k0);
#pragma unroll
    for (int nt = 0; nt < 2; ++nt) {
      int n = w * 32 + nt * 16 + l15;
      bf8_t b = ldv(wt + n * 128 + k0);
      acc[0][nt] = mfma16(a0, b, acc[0][nt]);
      acc[1][nt] = mfma16(a1, b, acc[1][nt]);
    }
  }
  float ps[2][4], pd[2][4];
#pragma unroll
  for (int mt = 0; mt < 2; ++mt)
#pragma unroll
    for (int r = 0; r < 4; ++r) { ps[mt][r] = 0.f; pd[mt][r] = 0.f; }
#pragma unroll
  for (int mt = 0; mt < 2; ++mt)
#pragma unroll
    for (int nt = 0; nt < 2; ++nt) {
      int col = w * 32 + nt * 16 + l15;
      float as = attsrc[col], ad = attdst[col];
#pragma unroll
      for (int r = 0; r < 4; ++r) {
        int row = mt * 16 + q * 4 + r;
        int rg = rowbase + row;
        float v = acc[mt][nt][r];
        if (rg < NN) hp16[(size_t)rg * 128 + col] = f2b(v);
        ps[mt][r] += v * as;
        pd[mt][r] += v * ad;
      }
    }
#pragma unroll
  for (int o = 1; o < 16; o <<= 1)
#pragma unroll
    for (int mt = 0; mt < 2; ++mt)
#pragma unroll
      for (int r = 0; r < 4; ++r) {
        ps[mt][r] += __shfl_xor(ps[mt][r], o);
        pd[mt][r] += __shfl_xor(pd[mt][r], o);
      }
  if (l15 == 0) {
#pragma unroll
    for (int mt = 0; mt < 2; ++mt)
#pragma unroll
      for (int r = 0; r < 4; ++r) {
        int rg = rowbase + mt * 16 + q * 4 + r;
        if (rg < NN) {
          asrc[rg * 4 + w] = ps[mt][r];
          adst[rg * 4 + w] = pd[mt][r];
        }
      }
  }
}

// ---------- GAT aggregation: 4 lanes/edge, 32 ch/lane, single pass ----------
template <int L, int FINAL>
__global__ __launch_bounds__(256) void agg_k(
    const int* __restrict__ indptr, const u16* __restrict__ recs,
    const float* __restrict__ asrc, const float* __restrict__ adst,
    const u16* __restrict__ hp16, const u16* __restrict__ feat16,
    const float* __restrict__ gbias, const float* __restrict__ lnw,
    const float* __restrict__ lnb, u16* __restrict__ gout16,
    float* __restrict__ out32) {
  const int wv = threadIdx.x >> 6, lane = threadIdx.x & 63;
  const int n = blockIdx.x * 4 + wv;
  const int g = lane >> 2, sl = lane & 3, cb = sl * 32;  // head == sl
  const int s0 = indptr[n], s1 = indptr[n + 1];
  const int dg = s1 - s0;
  const float advB = adst[n * 4 + sl];
  float ssp = 0.f, sap = 0.f;
  float acc[32];
#pragma unroll
  for (int i = 0; i < 32; ++i) acc[i] = 0.f;
  for (int base = s0; base < s1; base += 16) {
    int idx = base + g;
    int j = idx < s1 ? idx : s1 - 1;
    const u16* rp = recs + (size_t)j * 16;
    int sc = *(const int*)rp;
    float ae = h2f(rp[2 + 4 * L + sl]);
    float as = asrc[sc * 4 + sl];
    float l = as + advB + ae;
    l = fmaxf(l, 0.2f * l);
    float w = (idx < s1) ? __expf(l) : 0.f;
    ssp += w;
    sap += (idx < s1) ? ae : 0.f;
    const u16* hr = hp16 + (size_t)sc * 128 + cb;
    uint4 r0 = *(const uint4*)hr;
    uint4 r1 = *(const uint4*)(hr + 8);
    uint4 r2 = *(const uint4*)(hr + 16);
    uint4 r3 = *(const uint4*)(hr + 24);
    acc8(acc, r0, w);
    acc8(acc + 8, r1, w);
    acc8(acc + 16, r2, w);
    acc8(acc + 24, r3, w);
  }
  // reduce over the 16 edge-groups (offsets 4,8,16,32 flip g bits only)
#pragma unroll
  for (int i = 0; i < 32; ++i) {
    acc[i] += __shfl_xor(acc[i], 4);
    acc[i] += __shfl_xor(acc[i], 8);
    acc[i] += __shfl_xor(acc[i], 16);
    acc[i] += __shfl_xor(acc[i], 32);
  }
#pragma unroll
  for (int o = 4; o < 64; o <<= 1) { ssp += __shfl_xor(ssp, o); sap += __shfl_xor(sap, o); }
  // self-loop + normalization
  const float degf = (float)(dg > 0 ? dg : 1);
  float la = asrc[n * 4 + sl] + advB + sap / degf;
  la = fmaxf(la, 0.2f * la);
  float wsf = __expf(la);
  float inv = 1.f / (ssp + wsf + 1e-16f);
  // epilogue
  float selfr[32], resr[32];
  {
    const u16* hn = hp16 + (size_t)n * 128 + cb;
    const u16* fn = feat16 + (size_t)n * 128 + cb;
#pragma unroll
    for (int c = 0; c < 4; ++c) {
      unp8(*(const uint4*)(hn + c * 8), selfr + c * 8);
      unp8(*(const uint4*)(fn + c * 8), resr + c * 8);
    }
  }
  float v[32];
  float sum = 0.f, sq = 0.f;
#pragma unroll
  for (int i = 0; i < 32; ++i) {
    float vv = (acc[i] + wsf * selfr[i]) * inv + gbias[cb + i] + resr[i];
    vv = fminf(fmaxf(vv, -10.f), 10.f);
    v[i] = vv;
    sum += vv; sq += vv * vv;
  }
  sum += __shfl_xor(sum, 1); sq += __shfl_xor(sq, 1);
  sum += __shfl_xor(sum, 2); sq += __shfl_xor(sq, 2);
  float mu = sum * (1.f / 128.f);
  float var = sq * (1.f / 128.f) - mu * mu;
  float rstd = rsqrtf(var + 1e-5f);
  if (g == 0) {
    if (FINAL) {
#pragma unroll
      for (int c = 0; c < 8; ++c) {
        float4 o;
        float y0 = (v[c * 4 + 0] - mu) * rstd * lnw[cb + c * 4 + 0] + lnb[cb + c * 4 + 0];
        float y1 = (v[c * 4 + 1] - mu) * rstd * lnw[cb + c * 4 + 1] + lnb[cb + c * 4 + 1];
        float y2 = (v[c * 4 + 2] - mu) * rstd * lnw[cb + c * 4 + 2] + lnb[cb + c * 4 + 2];
        float y3 = (v[c * 4 + 3] - mu) * rstd * lnw[cb + c * 4 + 3] + lnb[cb + c * 4 + 3];
        o.x = y0 > 0.f ? y0 : expm1f(y0);
        o.y = y1 > 0.f ? y1 : expm1f(y1);
        o.z = y2 > 0.f ? y2 : expm1f(y2);
        o.w = y3 > 0.f ? y3 : expm1f(y3);
        *(float4*)(out32 + (size_t)n * 128 + cb + c * 4) = o;
      }
    } else {
#pragma unroll
      for (int c = 0; c < 4; ++c) {
        uint4 o;
        float y[8];
#pragma unroll
        for (int i = 0; i < 8; ++i) {
          int ch = cb + c * 8 + i;
          float yy = (v[c * 8 + i] - mu) * rstd * lnw[ch] + lnb[ch];
          y[i] = yy > 0.f ? yy : expm1f(yy);
        }
        o.x = (unsigned)f2b(y[0]) | ((unsigned)f2b(y[1]) << 16);
        o.y = (unsigned)f2b(y[2]) | ((unsigned)f2b(y[3]) << 16);
        o.z = (unsigned)f2b(y[4]) | ((unsigned)f2b(y[5]) << 16);
        o.w = (unsigned)f2b(y[6]) | ((unsigned)f2b(y[7]) << 16);
        *(uint4*)(gout16 + (size_t)n * 128 + cb + c * 8) = o;
      }
    }
  }
}

// ---------- launch ----------
extern "C" void kernel_launch(void* const* d_in, const int* in_sizes, int n_in,
                              void* d_out, int out_size, void* d_ws, size_t ws_size,
                              hipStream_t stream) {
  const float* x      = (const float*)d_in[0];
  const float* etime  = (const float*)d_in[1];
  const float* ip_w1  = (const float*)d_in[2];
  const float* ip_b1  = (const float*)d_in[3];
  const float* ip_lnw = (const float*)d_in[4];
  const float* ip_lnb = (const float*)d_in[5];
  const float* ip_w2  = (const float*)d_in[6];
  const float* ip_b2  = (const float*)d_in[7];
  const float* pn_w   = (const float*)d_in[8];
  const float* pn_b   = (const float*)d_in[9];
  const float* ta_w1  = (const float*)d_in[10];
  const float* ta_b1  = (const float*)d_in[11];
  const float* ta_lnw = (const float*)d_in[12];
  const float* ta_lnb = (const float*)d_in[13];
  const float* ta_w2  = (const float*)d_in[14];
  const float* ta_b2  = (const float*)d_in[15];
  const float* g1_w   = (const float*)d_in[16];
  const float* g1_as  = (const float*)d_in[17];
  const float* g1_ad  = (const float*)d_in[18];
  const float* g1_ew  = (const float*)d_in[19];
  const float* g1_ae  = (const float*)d_in[20];
  const float* g1_b   = (const float*)d_in[21];
  const float* g2_w   = (const float*)d_in[22];
  const float* g2_as  = (const float*)d_in[23];
  const float* g2_ad  = (const float*)d_in[24];
  const float* g2_ew  = (const float*)d_in[25];
  const float* g2_ae  = (const float*)d_in[26];
  const float* g2_b   = (const float*)d_in[27];
  const float* n1_w   = (const float*)d_in[28];
  const float* n1_b   = (const float*)d_in[29];
  const float* n2_w   = (const float*)d_in[30];
  const float* n2_b   = (const float*)d_in[31];
  const int* eidx     = (const int*)d_in[32];
  const int* srcv = eidx;
  const int* dstv = eidx + NE;

  char* p = (char*)d_ws;
  auto carve = [&](size_t bytes) -> char* {
    char* r = p;
    p += (bytes + 255) & ~(size_t)255;
    return r;
  };
  u16*   h16    = (u16*)carve((size_t)NN * 128 * 2);
  u16*   g16    = (u16*)carve((size_t)NN * 128 * 2);
  u16*   hp16   = (u16*)carve((size_t)NN * 128 * 2);
  float* asrc   = (float*)carve((size_t)NN * 4 * 4);
  float* adst   = (float*)carve((size_t)NN * 4 * 4);
  u16*   recs   = (u16*)carve((size_t)NE * 32);
  int*   deg    = (int*)carve((size_t)NN * 4);
  int*   indptr = (int*)carve((size_t)(NN + 1) * 4);
  int*   cursor = (int*)carve((size_t)NN * 4);
  int*   blks   = (int*)carve(512 * 4);
  float* V      = (float*)carve(128 * 8 * 4);
  float* tbl    = (float*)carve((size_t)TBLN * 8 * 4);
  u16*   w1t    = (u16*)carve(128 * 256 * 2);
  u16*   w2t    = (u16*)carve(256 * 128 * 2);
  u16*   g1wt   = (u16*)carve(128 * 128 * 2);
  u16*   g2wt   = (u16*)carve(128 * 128 * 2);

  hipMemsetAsync(deg, 0, (size_t)NN * 4, stream);
  hipMemsetAsync(cursor, 0, (size_t)NN * 4, stream);

  const int SCB = (NN + 511) / 512;  // 98

  prep_k<<<1 + 384 + FB, 256, 0, stream>>>(g1_ew, g1_ae, g2_ew, g2_ae, V,
                                           ip_w1, ip_w2, g1_w, g2_w,
                                           w1t, w2t, g1wt, g2wt, dstv, deg);
  build_table<<<TBLN, 128, 0, stream>>>(ta_w1, ta_b1, ta_lnw, ta_lnb, ta_w2, ta_b2, V, tbl);
  scan1<<<SCB, 512, 0, stream>>>(deg, indptr, blks);
  scan2<<<1, 128, 0, stream>>>(blks, SCB);
  scan3<<<SCB, 512, 0, stream>>>(indptr, blks);
  fillip_k<<<MB + FB, 256, 0, stream>>>(srcv, dstv, etime, tbl, indptr, cursor, recs,
                                        x, w1t, ip_b1, ip_lnw, ip_lnb, w2t, ip_b2,
                                        pn_w, pn_b, h16);
  hp_mfma<<<MB, 256, 0, stream>>>(h16, g1wt, g1_as, g1_ad, hp16, asrc, adst);
  agg_k<0, 0><<<NN / 4, 256, 0, stream>>>(indptr, recs, asrc, adst, hp16, h16,
                                          g1_b, n1_w, n1_b, g16, nullptr);
  hp_mfma<<<MB, 256, 0, stream>>>(g16, g2wt, g2_as, g2_ad, hp16, asrc, adst);
  agg_k<1, 1><<<NN / 4, 256, 0, stream>>>(indptr, recs, asrc, adst, hp16, g16,
                                          g2_b, n2_w, n2_b, nullptr, (float*)d_out);
}

// Round 8
// 399.315 us; speedup vs baseline: 1.4995x; 1.4995x over previous
//
#include <hip/hip_runtime.h>

typedef unsigned short u16;
typedef __attribute__((ext_vector_type(8))) short bf8_t;   // 8 bf16 in 4 VGPRs
typedef __attribute__((ext_vector_type(4))) float f4_t;

constexpr int NN   = 50000;
constexpr int NE   = 800000;
constexpr int TBLN = 2048;
constexpr int MB   = (NN + 31) / 32;  // 1563 ip blocks
constexpr int FB   = NE / 256;        // 3125 fill blocks

// ---------- helpers ----------
__device__ __forceinline__ float bf(const u16* p, int i) {
  return __uint_as_float(((unsigned)p[i]) << 16);
}
__device__ __forceinline__ u16 f2b(float f) {
  unsigned u = __float_as_uint(f);
  unsigned r = u + 0x7fffu + ((u >> 16) & 1u);  // RNE
  return (u16)(r >> 16);
}
__device__ __forceinline__ short f2bs(float f) {
  unsigned u = __float_as_uint(f);
  unsigned r = u + 0x7fffu + ((u >> 16) & 1u);
  return (short)(r >> 16);
}
__device__ __forceinline__ u16 f2h(float f) {
  _Float16 h = (_Float16)f;
  return __builtin_bit_cast(unsigned short, h);
}
__device__ __forceinline__ float h2f(u16 v) {
  _Float16 h = __builtin_bit_cast(_Float16, v);
  return (float)h;
}
__device__ __forceinline__ unsigned packh(float a, float b) {
  return (unsigned)f2h(a) | ((unsigned)f2h(b) << 16);
}
__device__ __forceinline__ float blo(unsigned u) { return __uint_as_float(u << 16); }
__device__ __forceinline__ float bhi(unsigned u) { return __uint_as_float(u & 0xffff0000u); }
__device__ __forceinline__ float wred64(float v) {
#pragma unroll
  for (int o = 32; o; o >>= 1) v += __shfl_xor(v, o);
  return v;
}
__device__ __forceinline__ bf8_t ldv(const u16* p) { return *(const bf8_t*)p; }
__device__ __forceinline__ bf8_t ldcvt(const float* p) {
  const float4 a = *(const float4*)p;
  const float4 b = *(const float4*)(p + 4);
  bf8_t r;
  r[0] = f2bs(a.x); r[1] = f2bs(a.y); r[2] = f2bs(a.z); r[3] = f2bs(a.w);
  r[4] = f2bs(b.x); r[5] = f2bs(b.y); r[6] = f2bs(b.z); r[7] = f2bs(b.w);
  return r;
}
__device__ __forceinline__ f4_t mfma16(bf8_t a, bf8_t b, f4_t c) {
  return __builtin_amdgcn_mfma_f32_16x16x32_bf16(a, b, c, 0, 0, 0);
}

// ---------- prep: build_V + weight transposes + deg histogram, one launch ----------
__global__ __launch_bounds__(256) void prep_k(
    const float* __restrict__ ew1, const float* __restrict__ ate1,
    const float* __restrict__ ew2, const float* __restrict__ ate2,
    float* __restrict__ V,
    const float* __restrict__ w1, const float* __restrict__ w2,
    const float* __restrict__ gw1, const float* __restrict__ gw2,
    u16* __restrict__ w1t, u16* __restrict__ w2t,
    u16* __restrict__ g1wt, u16* __restrict__ g2wt,
    const int* __restrict__ dstv, int* __restrict__ deg) {
  const int bid = blockIdx.x, t = threadIdx.x;
  if (bid == 0) {
#pragma unroll
    for (int rep = 0; rep < 2; ++rep) {
      int idx = t + rep * 256;
      int k = idx >> 2, hd = idx & 3;
      float s1 = 0.f, s2 = 0.f;
      for (int c = 0; c < 32; ++c) {
        s1 += ew1[k * 128 + hd * 32 + c] * ate1[hd * 32 + c];
        s2 += ew2[k * 128 + hd * 32 + c] * ate2[hd * 32 + c];
      }
      V[k * 8 + hd] = s1;
      V[k * 8 + 4 + hd] = s2;
    }
  } else if (bid <= 384) {
    int idx = (bid - 1) * 256 + t;
    if (idx < 32768) {
      int r = idx >> 8, c = idx & 255;
      w1t[c * 128 + r] = f2b(w1[idx]);
    } else if (idx < 65536) {
      int k = idx - 32768;
      int r = k >> 7, c = k & 127;
      w2t[c * 256 + r] = f2b(w2[k]);
    } else if (idx < 81920) {
      int k = idx - 65536;
      int r = k >> 7, c = k & 127;
      g1wt[c * 128 + r] = f2b(gw1[k]);
    } else {
      int k = idx - 81920;
      int r = k >> 7, c = k & 127;
      g2wt[c * 128 + r] = f2b(gw2[k]);
    }
  } else {
    int e = (bid - 385) * 256 + t;
    if (e < NE) atomicAdd(&deg[dstv[e]], 1);
  }
}

// ---------- tabulate a_edge(t) ----------
__global__ __launch_bounds__(128) void build_table(
    const float* __restrict__ taw1, const float* __restrict__ tab1,
    const float* __restrict__ talnw, const float* __restrict__ talnb,
    const float* __restrict__ taw2, const float* __restrict__ tab2,
    const float* __restrict__ V, float* __restrict__ tbl) {
  const int j = threadIdx.x;
  const int wv = j >> 6, ln = j & 63;
  const float t = (float)blockIdx.x / (float)(TBLN - 1);
  __shared__ float part[4];
  __shared__ float ush[128];
  __shared__ float pacc[16];
  float v = t * taw1[j] + tab1[j];
  float s = wred64(v), sq = wred64(v * v);
  if (ln == 0) { part[wv * 2] = s; part[wv * 2 + 1] = sq; }
  __syncthreads();
  float S = part[0] + part[2], SQ = part[1] + part[3];
  float mu = S * (1.f / 128.f);
  float var = SQ * (1.f / 128.f) - mu * mu;
  float rstd = rsqrtf(var + 1e-5f);
  float u = fmaxf((v - mu) * rstd * talnw[j] + talnb[j], 0.f);
  ush[j] = u;
  __syncthreads();
  float acc = 0.f;
  for (int k = 0; k < 128; ++k) acc += ush[k] * taw2[k * 128 + j];
  float w = tanhf(acc + tab2[j]);
  w = fminf(fmaxf(w, -3.f), 3.f);
#pragma unroll
  for (int p = 0; p < 8; ++p) {
    float z = wred64(w * V[j * 8 + p]);
    if (ln == 0) pacc[wv * 8 + p] = z;
  }
  __syncthreads();
  if (j < 8) tbl[blockIdx.x * 8 + j] = pacc[j] + pacc[8 + j];
}

// ---------- scans ----------
__global__ __launch_bounds__(512) void scan1(const int* __restrict__ deg,
                                             int* __restrict__ indptr,
                                             int* __restrict__ blks) {
  const int t = threadIdx.x;
  const int i = blockIdx.x * 512 + t;
  int v = (i < NN) ? deg[i] : 0;
  const int lane = t & 63, wv = t >> 6;
  int x = v;
#pragma unroll
  for (int o = 1; o < 64; o <<= 1) {
    int y = __shfl_up(x, o);
    if (lane >= o) x += y;
  }
  __shared__ int ws[8];
  if (lane == 63) ws[wv] = x;
  __syncthreads();
  if (t < 8) {
    int y = ws[t];
#pragma unroll
    for (int o = 1; o < 8; o <<= 1) {
      int z = __shfl_up(y, o);
      if (t >= o) y += z;
    }
    ws[t] = y;
  }
  __syncthreads();
  int excl = wv ? ws[wv - 1] : 0;
  x += excl;
  if (i < NN) indptr[i + 1] = x;
  if (t == 511) blks[blockIdx.x] = x;
}
__global__ void scan2(int* __restrict__ blks, int nb) {
  const int t = threadIdx.x;
  int v = (t < nb) ? blks[t] : 0;
  const int lane = t & 63, wv = t >> 6;
  int x = v;
#pragma unroll
  for (int o = 1; o < 64; o <<= 1) {
    int y = __shfl_up(x, o);
    if (lane >= o) x += y;
  }
  __shared__ int ws[2];
  if (lane == 63) ws[wv] = x;
  __syncthreads();
  if (wv == 1) x += ws[0];
  if (t < nb) blks[t] = x - v;
}
__global__ __launch_bounds__(512) void scan3(int* __restrict__ indptr,
                                             const int* __restrict__ blks) {
  const int i = blockIdx.x * 512 + threadIdx.x;
  if (i < NN) indptr[i + 1] += blks[blockIdx.x];
  if (i == 0) indptr[0] = 0;
}

// ---------- fused: CSR fill (latency) + input-projection MFMA (compute) ----------
__device__ void fill_body(int fb, const int* __restrict__ srcv,
                          const int* __restrict__ dstv,
                          const float* __restrict__ etime,
                          const float* __restrict__ tbl,
                          const int* __restrict__ indptr, int* __restrict__ cursor,
                          u16* __restrict__ recs) {
  const int e = fb * 256 + threadIdx.x;
  if (e >= NE) return;
  int d = dstv[e];
  int p = atomicAdd(&cursor[d], 1);
  int pos = indptr[d] + p;
  float t = etime[e];
  t = fminf(fmaxf(t, 0.f), 1.f);
  float fpos = t * (float)(TBLN - 1);
  int i0 = (int)fpos;
  if (i0 > TBLN - 2) i0 = TBLN - 2;
  float fr = fpos - (float)i0;
  const float4* r = (const float4*)(tbl + i0 * 8);
  float4 a0 = r[0], a1 = r[1], b0 = r[2], b1 = r[3];
  float4 o1, o2;
  o1.x = a0.x + fr * (b0.x - a0.x); o1.y = a0.y + fr * (b0.y - a0.y);
  o1.z = a0.z + fr * (b0.z - a0.z); o1.w = a0.w + fr * (b0.w - a0.w);
  o2.x = a1.x + fr * (b1.x - a1.x); o2.y = a1.y + fr * (b1.y - a1.y);
  o2.z = a1.z + fr * (b1.z - a1.z); o2.w = a1.w + fr * (b1.w - a1.w);
  u16* rp = recs + (size_t)pos * 16;
  uint4 w;
  w.x = (unsigned)srcv[e];
  w.y = packh(o1.x, o1.y);
  w.z = packh(o1.z, o1.w);
  w.w = packh(o2.x, o2.y);
  *(uint4*)rp = w;
  *(unsigned*)(rp + 8) = packh(o2.z, o2.w);
}

__device__ void ip_body(int ipb, char* smem,
                        const float* __restrict__ x, const u16* __restrict__ w1t,
                        const float* __restrict__ b1, const float* __restrict__ ln1w,
                        const float* __restrict__ ln1b, const u16* __restrict__ w2t,
                        const float* __restrict__ b2, const float* __restrict__ pnw,
                        const float* __restrict__ pnb, u16* __restrict__ h16) {
  float* h1f = (float*)smem;              // [32][260] fp32
  u16* h1n = (u16*)(smem + 33280);        // [32][264] bf16
  u16* h2n = h1n;

  const int t = threadIdx.x;
  const int w = t >> 6, lane = t & 63, q = lane >> 4, l15 = lane & 15;
  const int rowbase = ipb * 32;

  f4_t acc[2][4];
#pragma unroll
  for (int mt = 0; mt < 2; ++mt)
#pragma unroll
    for (int nt = 0; nt < 4; ++nt) acc[mt][nt] = (f4_t){0.f, 0.f, 0.f, 0.f};
#pragma unroll
  for (int kst = 0; kst < 4; ++kst) {
    int k0 = kst * 32 + q * 8;
    int r0 = rowbase + l15;      if (r0 > NN - 1) r0 = NN - 1;
    int r1 = rowbase + 16 + l15; if (r1 > NN - 1) r1 = NN - 1;
    bf8_t a0 = ldcvt(x + r0 * 128 + k0);
    bf8_t a1 = ldcvt(x + r1 * 128 + k0);
#pragma unroll
    for (int nt = 0; nt < 4; ++nt) {
      int n = w * 64 + nt * 16 + l15;
      bf8_t b = ldv(w1t + n * 128 + k0);
      acc[0][nt] = mfma16(a0, b, acc[0][nt]);
      acc[1][nt] = mfma16(a1, b, acc[1][nt]);
    }
  }
#pragma unroll
  for (int mt = 0; mt < 2; ++mt)
#pragma unroll
    for (int nt = 0; nt < 4; ++nt) {
      int col = w * 64 + nt * 16 + l15;
      float bb = b1[col];
#pragma unroll
      for (int r = 0; r < 4; ++r) {
        int row = mt * 16 + q * 4 + r;
        h1f[row * 260 + col] = fmaxf(acc[mt][nt][r] + bb, 0.f);
      }
    }
  __syncthreads();
  {
    const int row = t >> 3, sub = t & 7;
    const float* rp = h1f + row * 260;
    float sum = 0.f, sq = 0.f;
#pragma unroll
    for (int i = 0; i < 32; ++i) {
      float v = rp[sub + 8 * i];
      sum += v; sq += v * v;
    }
#pragma unroll
    for (int o = 1; o < 8; o <<= 1) { sum += __shfl_xor(sum, o); sq += __shfl_xor(sq, o); }
    float mu = sum * (1.f / 256.f);
    float var = sq * (1.f / 256.f) - mu * mu;
    float rstd = rsqrtf(var + 1e-5f);
#pragma unroll
    for (int i = 0; i < 32; ++i) {
      int c = sub + 8 * i;
      float v = (rp[c] - mu) * rstd * ln1w[c] + ln1b[c];
      h1n[row * 264 + c] = f2b(v);
    }
  }
  __syncthreads();
  f4_t acc2[2][2];
#pragma unroll
  for (int mt = 0; mt < 2; ++mt)
#pragma unroll
    for (int nt = 0; nt < 2; ++nt) acc2[mt][nt] = (f4_t){0.f, 0.f, 0.f, 0.f};
#pragma unroll
  for (int kst = 0; kst < 8; ++kst) {
    int k0 = kst * 32 + q * 8;
    bf8_t a0 = ldv(h1n + (l15) * 264 + k0);
    bf8_t a1 = ldv(h1n + (16 + l15) * 264 + k0);
#pragma unroll
    for (int nt = 0; nt < 2; ++nt) {
      int n = w * 32 + nt * 16 + l15;
      bf8_t b = ldv(w2t + n * 256 + k0);
      acc2[0][nt] = mfma16(a0, b, acc2[0][nt]);
      acc2[1][nt] = mfma16(a1, b, acc2[1][nt]);
    }
  }
  __syncthreads();
#pragma unroll
  for (int mt = 0; mt < 2; ++mt)
#pragma unroll
    for (int nt = 0; nt < 2; ++nt) {
      int col = w * 32 + nt * 16 + l15;
      float bb = b2[col];
#pragma unroll
      for (int r = 0; r < 4; ++r) {
        int row = mt * 16 + q * 4 + r;
        h1f[row * 132 + col] = acc2[mt][nt][r] + bb;
      }
    }
  __syncthreads();
  {
    const int row = t >> 3, sub = t & 7;
    const float* rp = h1f + row * 132;
    float sum = 0.f, sq = 0.f;
#pragma unroll
    for (int i = 0; i < 16; ++i) {
      float v = rp[sub + 8 * i];
      sum += v; sq += v * v;
    }
#pragma unroll
    for (int o = 1; o < 8; o <<= 1) { sum += __shfl_xor(sum, o); sq += __shfl_xor(sq, o); }
    float mu = sum * (1.f / 128.f);
    float var = sq * (1.f / 128.f) - mu * mu;
    float rstd = rsqrtf(var + 1e-5f);
#pragma unroll
    for (int i = 0; i < 16; ++i) {
      int c = sub + 8 * i;
      float v = (rp[c] - mu) * rstd * pnw[c] + pnb[c];
      v = fminf(fmaxf(v, 0.f), 10.f);
      h2n[row * 128 + c] = f2b(v);
    }
  }
  __syncthreads();
  {
    const int row = t >> 3, cb = (t & 7) * 16;
    int rg = rowbase + row;
    if (rg < NN) {
      uint4 v0 = *(const uint4*)(h2n + row * 128 + cb);
      uint4 v1 = *(const uint4*)(h2n + row * 128 + cb + 8);
      *(uint4*)(h16 + rg * 128 + cb) = v0;
      *(uint4*)(h16 + rg * 128 + cb + 8) = v1;
    }
  }
}

__global__ __launch_bounds__(256) void fillip_k(
    const int* srcv, const int* dstv, const float* etime, const float* tbl,
    const int* indptr, int* cursor, u16* recs,
    const float* x, const u16* w1t, const float* b1, const float* ln1w,
    const float* ln1b, const u16* w2t, const float* b2, const float* pnw,
    const float* pnb, u16* h16) {
  __shared__ char smem[50176];
  const int bid = blockIdx.x;
  if (bid % 3 == 0) {
    ip_body(bid / 3, smem, x, w1t, b1, ln1w, ln1b, w2t, b2, pnw, pnb, h16);
  } else {
    fill_body(bid - bid / 3 - 1, srcv, dstv, etime, tbl, indptr, cursor, recs);
  }
}

// ---------- MFMA node projection + attention logits ----------
__global__ __launch_bounds__(256) void hp_mfma(
    const u16* __restrict__ feat16, const u16* __restrict__ wt,
    const float* __restrict__ attsrc, const float* __restrict__ attdst,
    u16* __restrict__ hp16, float* __restrict__ asrc, float* __restrict__ adst) {
  const int t = threadIdx.x;
  const int w = t >> 6, lane = t & 63, q = lane >> 4, l15 = lane & 15;
  const int rowbase = blockIdx.x * 32;
  f4_t acc[2][2];
#pragma unroll
  for (int mt = 0; mt < 2; ++mt)
#pragma unroll
    for (int nt = 0; nt < 2; ++nt) acc[mt][nt] = (f4_t){0.f, 0.f, 0.f, 0.f};
#pragma unroll
  for (int kst = 0; kst < 4; ++kst) {
    int k0 = kst * 32 + q * 8;
    int r0 = rowbase + l15;      if (r0 > NN - 1) r0 = NN - 1;
    int r1 = rowbase + 16 + l15; if (r1 > NN - 1) r1 = NN - 1;
    bf8_t a0 = ldv(feat16 + r0 * 128 + k0);
    bf8_t a1 = ldv(feat16 + r1 * 128 + k0);
#pragma unroll
    for (int nt = 0; nt < 2; ++nt) {
      int n = w * 32 + nt * 16 + l15;
      bf8_t b = ldv(wt + n * 128 + k0);
      acc[0][nt] = mfma16(a0, b, acc[0][nt]);
      acc[1][nt] = mfma16(a1, b, acc[1][nt]);
    }
  }
  float ps[2][4], pd[2][4];
#pragma unroll
  for (int mt = 0; mt < 2; ++mt)
#pragma unroll
    for (int r = 0; r < 4; ++r) { ps[mt][r] = 0.f; pd[mt][r] = 0.f; }
#pragma unroll
  for (int mt = 0; mt < 2; ++mt)
#pragma unroll
    for (int nt = 0; nt < 2; ++nt) {
      int col = w * 32 + nt * 16 + l15;
      float as = attsrc[col], ad = attdst[col];
#pragma unroll
      for (int r = 0; r < 4; ++r) {
        int row = mt * 16 + q * 4 + r;
        int rg = rowbase + row;
        float v = acc[mt][nt][r];
        if (rg < NN) hp16[(size_t)rg * 128 + col] = f2b(v);
        ps[mt][r] += v * as;
        pd[mt][r] += v * ad;
      }
    }
#pragma unroll
  for (int o = 1; o < 16; o <<= 1)
#pragma unroll
    for (int mt = 0; mt < 2; ++mt)
#pragma unroll
      for (int r = 0; r < 4; ++r) {
        ps[mt][r] += __shfl_xor(ps[mt][r], o);
        pd[mt][r] += __shfl_xor(pd[mt][r], o);
      }
  if (l15 == 0) {
#pragma unroll
    for (int mt = 0; mt < 2; ++mt)
#pragma unroll
      for (int r = 0; r < 4; ++r) {
        int rg = rowbase + mt * 16 + q * 4 + r;
        if (rg < NN) {
          asrc[rg * 4 + w] = ps[mt][r];
          adst[rg * 4 + w] = pd[mt][r];
        }
      }
  }
}

// ---------- GAT aggregation: single pass, 16-lane x 8-ch layout (round-6) ----------
template <int L, int FINAL>
__global__ __launch_bounds__(256) void agg_k(
    const int* __restrict__ indptr, const u16* __restrict__ recs,
    const float* __restrict__ asrc, const float* __restrict__ adst,
    const u16* __restrict__ hp16, const u16* __restrict__ feat16,
    const float* __restrict__ gbias, const float* __restrict__ lnw,
    const float* __restrict__ lnb, u16* __restrict__ gout16,
    float* __restrict__ out32) {
  const int wv = threadIdx.x >> 6, lane = threadIdx.x & 63;
  const int n = blockIdx.x * 4 + wv;
  if (n >= NN) return;
  const int s0 = indptr[n], s1 = indptr[n + 1];
  const int dg = s1 - s0;
  const int g = lane >> 4, sl = lane & 15, cb = sl * 8, hdB = sl >> 2;
  const float advB = adst[n * 4 + hdB];
  float ssp = 0.f, sap = 0.f;
  float acc[8];
#pragma unroll
  for (int i = 0; i < 8; ++i) acc[i] = 0.f;
  for (int base = s0; base < s1; base += 8) {
    int i0 = base + g, i1 = base + 4 + g;
    int j0 = i0 < s1 ? i0 : s1 - 1;
    int j1 = i1 < s1 ? i1 : s1 - 1;
    const u16* r0 = recs + (size_t)j0 * 16;
    const u16* r1 = recs + (size_t)j1 * 16;
    int sc0 = *(const int*)r0, sc1 = *(const int*)r1;
    float ae0 = h2f(r0[2 + 4 * L + hdB]);
    float ae1v = h2f(r1[2 + 4 * L + hdB]);
    float as0 = asrc[sc0 * 4 + hdB], as1 = asrc[sc1 * 4 + hdB];
    const uint4 row0 = *(const uint4*)(hp16 + (size_t)sc0 * 128 + cb);
    const uint4 row1 = *(const uint4*)(hp16 + (size_t)sc1 * 128 + cb);
    float l0 = as0 + advB + ae0; l0 = fmaxf(l0, 0.2f * l0);
    float l1 = as1 + advB + ae1v; l1 = fmaxf(l1, 0.2f * l1);
    float w0 = (i0 < s1) ? __expf(l0) : 0.f;
    float w1 = (i1 < s1) ? __expf(l1) : 0.f;
    ssp += w0 + w1;
    sap += ((i0 < s1) ? ae0 : 0.f) + ((i1 < s1) ? ae1v : 0.f);
    acc[0] += w0 * blo(row0.x) + w1 * blo(row1.x);
    acc[1] += w0 * bhi(row0.x) + w1 * bhi(row1.x);
    acc[2] += w0 * blo(row0.y) + w1 * blo(row1.y);
    acc[3] += w0 * bhi(row0.y) + w1 * bhi(row1.y);
    acc[4] += w0 * blo(row0.z) + w1 * blo(row1.z);
    acc[5] += w0 * bhi(row0.z) + w1 * bhi(row1.z);
    acc[6] += w0 * blo(row0.w) + w1 * blo(row1.w);
    acc[7] += w0 * bhi(row0.w) + w1 * bhi(row1.w);
  }
  // reduce across the 4 edge-groups
#pragma unroll
  for (int i = 0; i < 8; ++i) {
    acc[i] += __shfl_xor(acc[i], 16);
    acc[i] += __shfl_xor(acc[i], 32);
  }
  ssp += __shfl_xor(ssp, 16); ssp += __shfl_xor(ssp, 32);
  sap += __shfl_xor(sap, 16); sap += __shfl_xor(sap, 32);
  // self-loop (fill_value='mean' fold) + normalization
  const float degf = (float)(dg > 0 ? dg : 1);
  float asnB = asrc[n * 4 + hdB];
  float la = asnB + advB + sap / degf;
  la = fmaxf(la, 0.2f * la);
  float wsf = __expf(la);
  float inv = 1.f / (ssp + wsf + 1e-16f);
  // epilogue
  const uint4 rs4 = *(const uint4*)(hp16 + (size_t)n * 128 + cb);
  const uint4 rr4 = *(const uint4*)(feat16 + (size_t)n * 128 + cb);
  const float4 gb0 = *(const float4*)(gbias + cb);
  const float4 gb1 = *(const float4*)(gbias + cb + 4);
  float v[8];
  v[0] = (acc[0] + wsf * blo(rs4.x)) * inv + gb0.x + blo(rr4.x);
  v[1] = (acc[1] + wsf * bhi(rs4.x)) * inv + gb0.y + bhi(rr4.x);
  v[2] = (acc[2] + wsf * blo(rs4.y)) * inv + gb0.z + blo(rr4.y);
  v[3] = (acc[3] + wsf * bhi(rs4.y)) * inv + gb0.w + bhi(rr4.y);
  v[4] = (acc[4] + wsf * blo(rs4.z)) * inv + gb1.x + blo(rr4.z);
  v[5] = (acc[5] + wsf * bhi(rs4.z)) * inv + gb1.y + bhi(rr4.z);
  v[6] = (acc[6] + wsf * blo(rs4.w)) * inv + gb1.z + blo(rr4.w);
  v[7] = (acc[7] + wsf * bhi(rs4.w)) * inv + gb1.w + bhi(rr4.w);
  float sum = 0.f, sq = 0.f;
#pragma unroll
  for (int i = 0; i < 8; ++i) {
    v[i] = fminf(fmaxf(v[i], -10.f), 10.f);
    sum += v[i]; sq += v[i] * v[i];
  }
#pragma unroll
  for (int o = 1; o < 16; o <<= 1) {
    sum += __shfl_xor(sum, o);
    sq += __shfl_xor(sq, o);
  }
  float mu = sum * (1.f / 128.f);
  float var = sq * (1.f / 128.f) - mu * mu;
  float rstd = rsqrtf(var + 1e-5f);
  const float4 lw0 = *(const float4*)(lnw + cb);
  const float4 lw1 = *(const float4*)(lnw + cb + 4);
  const float4 lb0 = *(const float4*)(lnb + cb);
  const float4 lb1 = *(const float4*)(lnb + cb + 4);
  float y[8];
  y[0] = (v[0] - mu) * rstd * lw0.x + lb0.x;
  y[1] = (v[1] - mu) * rstd * lw0.y + lb0.y;
  y[2] = (v[2] - mu) * rstd * lw0.z + lb0.z;
  y[3] = (v[3] - mu) * rstd * lw0.w + lb0.w;
  y[4] = (v[4] - mu) * rstd * lw1.x + lb1.x;
  y[5] = (v[5] - mu) * rstd * lw1.y + lb1.y;
  y[6] = (v[6] - mu) * rstd * lw1.z + lb1.z;
  y[7] = (v[7] - mu) * rstd * lw1.w + lb1.w;
#pragma unroll
  for (int i = 0; i < 8; ++i) y[i] = y[i] > 0.f ? y[i] : expm1f(y[i]);
  if (g == 0) {
    if (FINAL) {
      float4 o0 = {y[0], y[1], y[2], y[3]};
      float4 o1 = {y[4], y[5], y[6], y[7]};
      *(float4*)(out32 + (size_t)n * 128 + cb) = o0;
      *(float4*)(out32 + (size_t)n * 128 + cb + 4) = o1;
    } else {
      uint4 o;
      o.x = (unsigned)f2b(y[0]) | ((unsigned)f2b(y[1]) << 16);
      o.y = (unsigned)f2b(y[2]) | ((unsigned)f2b(y[3]) << 16);
      o.z = (unsigned)f2b(y[4]) | ((unsigned)f2b(y[5]) << 16);
      o.w = (unsigned)f2b(y[6]) | ((unsigned)f2b(y[7]) << 16);
      *(uint4*)(gout16 + (size_t)n * 128 + cb) = o;
    }
  }
}

// ---------- launch ----------
extern "C" void kernel_launch(void* const* d_in, const int* in_sizes, int n_in,
                              void* d_out, int out_size, void* d_ws, size_t ws_size,
                              hipStream_t stream) {
  const float* x      = (const float*)d_in[0];
  const float* etime  = (const float*)d_in[1];
  const float* ip_w1  = (const float*)d_in[2];
  const float* ip_b1  = (const float*)d_in[3];
  const float* ip_lnw = (const float*)d_in[4];
  const float* ip_lnb = (const float*)d_in[5];
  const float* ip_w2  = (const float*)d_in[6];
  const float* ip_b2  = (const float*)d_in[7];
  const float* pn_w   = (const float*)d_in[8];
  const float* pn_b   = (const float*)d_in[9];
  const float* ta_w1  = (const float*)d_in[10];
  const float* ta_b1  = (const float*)d_in[11];
  const float* ta_lnw = (const float*)d_in[12];
  const float* ta_lnb = (const float*)d_in[13];
  const float* ta_w2  = (const float*)d_in[14];
  const float* ta_b2  = (const float*)d_in[15];
  const float* g1_w   = (const float*)d_in[16];
  const float* g1_as  = (const float*)d_in[17];
  const float* g1_ad  = (const float*)d_in[18];
  const float* g1_ew  = (const float*)d_in[19];
  const float* g1_ae  = (const float*)d_in[20];
  const float* g1_b   = (const float*)d_in[21];
  const float* g2_w   = (const float*)d_in[22];
  const float* g2_as  = (const float*)d_in[23];
  const float* g2_ad  = (const float*)d_in[24];
  const float* g2_ew  = (const float*)d_in[25];
  const float* g2_ae  = (const float*)d_in[26];
  const float* g2_b   = (const float*)d_in[27];
  const float* n1_w   = (const float*)d_in[28];
  const float* n1_b   = (const float*)d_in[29];
  const float* n2_w   = (const float*)d_in[30];
  const float* n2_b   = (const float*)d_in[31];
  const int* eidx     = (const int*)d_in[32];
  const int* srcv = eidx;
  const int* dstv = eidx + NE;

  char* p = (char*)d_ws;
  auto carve = [&](size_t bytes) -> char* {
    char* r = p;
    p += (bytes + 255) & ~(size_t)255;
    return r;
  };
  u16*   h16    = (u16*)carve((size_t)NN * 128 * 2);
  u16*   g16    = (u16*)carve((size_t)NN * 128 * 2);
  u16*   hp16   = (u16*)carve((size_t)NN * 128 * 2);
  float* asrc   = (float*)carve((size_t)NN * 4 * 4);
  float* adst   = (float*)carve((size_t)NN * 4 * 4);
  u16*   recs   = (u16*)carve((size_t)NE * 32);
  int*   deg    = (int*)carve((size_t)NN * 4);
  int*   indptr = (int*)carve((size_t)(NN + 1) * 4);
  int*   cursor = (int*)carve((size_t)NN * 4);
  int*   blks   = (int*)carve(512 * 4);
  float* V      = (float*)carve(128 * 8 * 4);
  float* tbl    = (float*)carve((size_t)TBLN * 8 * 4);
  u16*   w1t    = (u16*)carve(128 * 256 * 2);
  u16*   w2t    = (u16*)carve(256 * 128 * 2);
  u16*   g1wt   = (u16*)carve(128 * 128 * 2);
  u16*   g2wt   = (u16*)carve(128 * 128 * 2);

  hipMemsetAsync(deg, 0, (size_t)NN * 4, stream);
  hipMemsetAsync(cursor, 0, (size_t)NN * 4, stream);

  const int SCB = (NN + 511) / 512;  // 98

  prep_k<<<1 + 384 + FB, 256, 0, stream>>>(g1_ew, g1_ae, g2_ew, g2_ae, V,
                                           ip_w1, ip_w2, g1_w, g2_w,
                                           w1t, w2t, g1wt, g2wt, dstv, deg);
  build_table<<<TBLN, 128, 0, stream>>>(ta_w1, ta_b1, ta_lnw, ta_lnb, ta_w2, ta_b2, V, tbl);
  scan1<<<SCB, 512, 0, stream>>>(deg, indptr, blks);
  scan2<<<1, 128, 0, stream>>>(blks, SCB);
  scan3<<<SCB, 512, 0, stream>>>(indptr, blks);
  fillip_k<<<MB + FB, 256, 0, stream>>>(srcv, dstv, etime, tbl, indptr, cursor, recs,
                                        x, w1t, ip_b1, ip_lnw, ip_lnb, w2t, ip_b2,
                                        pn_w, pn_b, h16);
  hp_mfma<<<MB, 256, 0, stream>>>(h16, g1wt, g1_as, g1_ad, hp16, asrc, adst);
  agg_k<0, 0><<<NN / 4, 256, 0, stream>>>(indptr, recs, asrc, adst, hp16, h16,
                                          g1_b, n1_w, n1_b, g16, nullptr);
  hp_mfma<<<MB, 256, 0, stream>>>(g16, g2wt, g2_as, g2_ad, hp16, asrc, adst);
  agg_k<1, 1><<<NN / 4, 256, 0, stream>>>(indptr, recs, asrc, adst, hp16, g16,
                                          g2_b, n2_w, n2_b, nullptr, (float*)d_out);
}

// Round 9
// 398.208 us; speedup vs baseline: 1.5037x; 1.0028x over previous
//
#include <hip/hip_runtime.h>

typedef unsigned short u16;
typedef __attribute__((ext_vector_type(8))) short bf8_t;   // 8 bf16 in 4 VGPRs
typedef __attribute__((ext_vector_type(4))) float f4_t;

constexpr int NN   = 50000;
constexpr int NE   = 800000;
constexpr int TBLN = 2048;
constexpr int MB   = (NN + 31) / 32;  // 1563 ip blocks
constexpr int FB   = NE / 256;        // 3125 fill blocks

// ---------- helpers ----------
__device__ __forceinline__ float bf(const u16* p, int i) {
  return __uint_as_float(((unsigned)p[i]) << 16);
}
__device__ __forceinline__ u16 f2b(float f) {
  unsigned u = __float_as_uint(f);
  unsigned r = u + 0x7fffu + ((u >> 16) & 1u);  // RNE
  return (u16)(r >> 16);
}
__device__ __forceinline__ short f2bs(float f) {
  unsigned u = __float_as_uint(f);
  unsigned r = u + 0x7fffu + ((u >> 16) & 1u);
  return (short)(r >> 16);
}
__device__ __forceinline__ u16 f2h(float f) {
  _Float16 h = (_Float16)f;
  return __builtin_bit_cast(unsigned short, h);
}
__device__ __forceinline__ float h2f(u16 v) {
  _Float16 h = __builtin_bit_cast(_Float16, v);
  return (float)h;
}
__device__ __forceinline__ unsigned packh(float a, float b) {
  return (unsigned)f2h(a) | ((unsigned)f2h(b) << 16);
}
__device__ __forceinline__ float blo(unsigned u) { return __uint_as_float(u << 16); }
__device__ __forceinline__ float bhi(unsigned u) { return __uint_as_float(u & 0xffff0000u); }
__device__ __forceinline__ float wred64(float v) {
#pragma unroll
  for (int o = 32; o; o >>= 1) v += __shfl_xor(v, o);
  return v;
}
__device__ __forceinline__ bf8_t ldv(const u16* p) { return *(const bf8_t*)p; }
__device__ __forceinline__ bf8_t ldcvt(const float* p) {
  const float4 a = *(const float4*)p;
  const float4 b = *(const float4*)(p + 4);
  bf8_t r;
  r[0] = f2bs(a.x); r[1] = f2bs(a.y); r[2] = f2bs(a.z); r[3] = f2bs(a.w);
  r[4] = f2bs(b.x); r[5] = f2bs(b.y); r[6] = f2bs(b.z); r[7] = f2bs(b.w);
  return r;
}
__device__ __forceinline__ f4_t mfma16(bf8_t a, bf8_t b, f4_t c) {
  return __builtin_amdgcn_mfma_f32_16x16x32_bf16(a, b, c, 0, 0, 0);
}

// ---------- prep: build_V + weight transposes + deg histogram, one launch ----------
__global__ __launch_bounds__(256) void prep_k(
    const float* __restrict__ ew1, const float* __restrict__ ate1,
    const float* __restrict__ ew2, const float* __restrict__ ate2,
    float* __restrict__ V,
    const float* __restrict__ w1, const float* __restrict__ w2,
    const float* __restrict__ gw1, const float* __restrict__ gw2,
    u16* __restrict__ w1t, u16* __restrict__ w2t,
    u16* __restrict__ g1wt, u16* __restrict__ g2wt,
    const int* __restrict__ dstv, int* __restrict__ deg) {
  const int bid = blockIdx.x, t = threadIdx.x;
  if (bid == 0) {
#pragma unroll
    for (int rep = 0; rep < 2; ++rep) {
      int idx = t + rep * 256;
      int k = idx >> 2, hd = idx & 3;
      float s1 = 0.f, s2 = 0.f;
      for (int c = 0; c < 32; ++c) {
        s1 += ew1[k * 128 + hd * 32 + c] * ate1[hd * 32 + c];
        s2 += ew2[k * 128 + hd * 32 + c] * ate2[hd * 32 + c];
      }
      V[k * 8 + hd] = s1;
      V[k * 8 + 4 + hd] = s2;
    }
  } else if (bid <= 384) {
    int idx = (bid - 1) * 256 + t;
    if (idx < 32768) {
      int r = idx >> 8, c = idx & 255;
      w1t[c * 128 + r] = f2b(w1[idx]);
    } else if (idx < 65536) {
      int k = idx - 32768;
      int r = k >> 7, c = k & 127;
      w2t[c * 256 + r] = f2b(w2[k]);
    } else if (idx < 81920) {
      int k = idx - 65536;
      int r = k >> 7, c = k & 127;
      g1wt[c * 128 + r] = f2b(gw1[k]);
    } else {
      int k = idx - 81920;
      int r = k >> 7, c = k & 127;
      g2wt[c * 128 + r] = f2b(gw2[k]);
    }
  } else {
    int e = (bid - 385) * 256 + t;
    if (e < NE) atomicAdd(&deg[dstv[e]], 1);
  }
}

// ---------- tabulate a_edge(t) ----------
__global__ __launch_bounds__(128) void build_table(
    const float* __restrict__ taw1, const float* __restrict__ tab1,
    const float* __restrict__ talnw, const float* __restrict__ talnb,
    const float* __restrict__ taw2, const float* __restrict__ tab2,
    const float* __restrict__ V, float* __restrict__ tbl) {
  const int j = threadIdx.x;
  const int wv = j >> 6, ln = j & 63;
  const float t = (float)blockIdx.x / (float)(TBLN - 1);
  __shared__ float part[4];
  __shared__ float ush[128];
  __shared__ float pacc[16];
  float v = t * taw1[j] + tab1[j];
  float s = wred64(v), sq = wred64(v * v);
  if (ln == 0) { part[wv * 2] = s; part[wv * 2 + 1] = sq; }
  __syncthreads();
  float S = part[0] + part[2], SQ = part[1] + part[3];
  float mu = S * (1.f / 128.f);
  float var = SQ * (1.f / 128.f) - mu * mu;
  float rstd = rsqrtf(var + 1e-5f);
  float u = fmaxf((v - mu) * rstd * talnw[j] + talnb[j], 0.f);
  ush[j] = u;
  __syncthreads();
  float acc = 0.f;
  for (int k = 0; k < 128; ++k) acc += ush[k] * taw2[k * 128 + j];
  float w = tanhf(acc + tab2[j]);
  w = fminf(fmaxf(w, -3.f), 3.f);
#pragma unroll
  for (int p = 0; p < 8; ++p) {
    float z = wred64(w * V[j * 8 + p]);
    if (ln == 0) pacc[wv * 8 + p] = z;
  }
  __syncthreads();
  if (j < 8) tbl[blockIdx.x * 8 + j] = pacc[j] + pacc[8 + j];
}

// ---------- scans ----------
__global__ __launch_bounds__(512) void scan1(const int* __restrict__ deg,
                                             int* __restrict__ indptr,
                                             int* __restrict__ blks) {
  const int t = threadIdx.x;
  const int i = blockIdx.x * 512 + t;
  int v = (i < NN) ? deg[i] : 0;
  const int lane = t & 63, wv = t >> 6;
  int x = v;
#pragma unroll
  for (int o = 1; o < 64; o <<= 1) {
    int y = __shfl_up(x, o);
    if (lane >= o) x += y;
  }
  __shared__ int ws[8];
  if (lane == 63) ws[wv] = x;
  __syncthreads();
  if (t < 8) {
    int y = ws[t];
#pragma unroll
    for (int o = 1; o < 8; o <<= 1) {
      int z = __shfl_up(y, o);
      if (t >= o) y += z;
    }
    ws[t] = y;
  }
  __syncthreads();
  int excl = wv ? ws[wv - 1] : 0;
  x += excl;
  if (i < NN) indptr[i + 1] = x;
  if (t == 511) blks[blockIdx.x] = x;
}
__global__ void scan2(int* __restrict__ blks, int nb) {
  const int t = threadIdx.x;
  int v = (t < nb) ? blks[t] : 0;
  const int lane = t & 63, wv = t >> 6;
  int x = v;
#pragma unroll
  for (int o = 1; o < 64; o <<= 1) {
    int y = __shfl_up(x, o);
    if (lane >= o) x += y;
  }
  __shared__ int ws[2];
  if (lane == 63) ws[wv] = x;
  __syncthreads();
  if (wv == 1) x += ws[0];
  if (t < nb) blks[t] = x - v;
}
__global__ __launch_bounds__(512) void scan3(int* __restrict__ indptr,
                                             const int* __restrict__ blks) {
  const int i = blockIdx.x * 512 + threadIdx.x;
  if (i < NN) indptr[i + 1] += blks[blockIdx.x];
  if (i == 0) indptr[0] = 0;
}

// ---------- fused: CSR fill (latency) + input-projection MFMA (compute) ----------
__device__ void fill_body(int fb, const int* __restrict__ srcv,
                          const int* __restrict__ dstv,
                          const float* __restrict__ etime,
                          const float* __restrict__ tbl,
                          const int* __restrict__ indptr, int* __restrict__ cursor,
                          u16* __restrict__ recs) {
  const int e = fb * 256 + threadIdx.x;
  if (e >= NE) return;
  int d = dstv[e];
  int p = atomicAdd(&cursor[d], 1);
  int pos = indptr[d] + p;
  float t = etime[e];
  t = fminf(fmaxf(t, 0.f), 1.f);
  float fpos = t * (float)(TBLN - 1);
  int i0 = (int)fpos;
  if (i0 > TBLN - 2) i0 = TBLN - 2;
  float fr = fpos - (float)i0;
  const float4* r = (const float4*)(tbl + i0 * 8);
  float4 a0 = r[0], a1 = r[1], b0 = r[2], b1 = r[3];
  float4 o1, o2;
  o1.x = a0.x + fr * (b0.x - a0.x); o1.y = a0.y + fr * (b0.y - a0.y);
  o1.z = a0.z + fr * (b0.z - a0.z); o1.w = a0.w + fr * (b0.w - a0.w);
  o2.x = a1.x + fr * (b1.x - a1.x); o2.y = a1.y + fr * (b1.y - a1.y);
  o2.z = a1.z + fr * (b1.z - a1.z); o2.w = a1.w + fr * (b1.w - a1.w);
  u16* rp = recs + (size_t)pos * 16;
  uint4 w;
  w.x = (unsigned)srcv[e];
  w.y = packh(o1.x, o1.y);
  w.z = packh(o1.z, o1.w);
  w.w = packh(o2.x, o2.y);
  *(uint4*)rp = w;
  *(unsigned*)(rp + 8) = packh(o2.z, o2.w);
}

// register-LN input projection: LDS = h1n[32][264] bf16 (aliased h2n) + part[4][32]x2
__device__ void ip_body(int ipb, char* smem,
                        const float* __restrict__ x, const u16* __restrict__ w1t,
                        const float* __restrict__ b1, const float* __restrict__ ln1w,
                        const float* __restrict__ ln1b, const u16* __restrict__ w2t,
                        const float* __restrict__ b2, const float* __restrict__ pnw,
                        const float* __restrict__ pnb, u16* __restrict__ h16) {
  u16* h1n = (u16*)smem;                       // [32][264] bf16
  u16* h2n = h1n;                              // alias, [32][128] after GEMM2
  float* partS = (float*)(smem + 16896);       // [4][32]
  float* partQ = (float*)(smem + 16896 + 512); // [4][32]

  const int t = threadIdx.x;
  const int w = t >> 6, lane = t & 63, q = lane >> 4, l15 = lane & 15;
  const int rowbase = ipb * 32;

  // ---- GEMM1: [32,128] @ [128,256] ----
  f4_t acc[2][4];
#pragma unroll
  for (int mt = 0; mt < 2; ++mt)
#pragma unroll
    for (int nt = 0; nt < 4; ++nt) acc[mt][nt] = (f4_t){0.f, 0.f, 0.f, 0.f};
#pragma unroll
  for (int kst = 0; kst < 4; ++kst) {
    int k0 = kst * 32 + q * 8;
    int r0 = rowbase + l15;      if (r0 > NN - 1) r0 = NN - 1;
    int r1 = rowbase + 16 + l15; if (r1 > NN - 1) r1 = NN - 1;
    bf8_t a0 = ldcvt(x + r0 * 128 + k0);
    bf8_t a1 = ldcvt(x + r1 * 128 + k0);
#pragma unroll
    for (int nt = 0; nt < 4; ++nt) {
      int n = w * 64 + nt * 16 + l15;
      bf8_t b = ldv(w1t + n * 128 + k0);
      acc[0][nt] = mfma16(a0, b, acc[0][nt]);
      acc[1][nt] = mfma16(a1, b, acc[1][nt]);
    }
  }
  // bias + relu in regs
#pragma unroll
  for (int nt = 0; nt < 4; ++nt) {
    float bb = b1[w * 64 + nt * 16 + l15];
#pragma unroll
    for (int mt = 0; mt < 2; ++mt)
#pragma unroll
      for (int r = 0; r < 4; ++r)
        acc[mt][nt][r] = fmaxf(acc[mt][nt][r] + bb, 0.f);
  }
  // per-(mt,r) partial row sums over this wave's 64 cols
  {
    float s[2][4], sq[2][4];
#pragma unroll
    for (int mt = 0; mt < 2; ++mt)
#pragma unroll
      for (int r = 0; r < 4; ++r) {
        float a = acc[mt][0][r], b = acc[mt][1][r], c = acc[mt][2][r], d = acc[mt][3][r];
        s[mt][r] = a + b + c + d;
        sq[mt][r] = a * a + b * b + c * c + d * d;
      }
#pragma unroll
    for (int o = 1; o < 16; o <<= 1)
#pragma unroll
      for (int mt = 0; mt < 2; ++mt)
#pragma unroll
        for (int r = 0; r < 4; ++r) {
          s[mt][r] += __shfl_xor(s[mt][r], o);
          sq[mt][r] += __shfl_xor(sq[mt][r], o);
        }
    if (l15 == 0) {
#pragma unroll
      for (int mt = 0; mt < 2; ++mt)
#pragma unroll
        for (int r = 0; r < 4; ++r) {
          int row = mt * 16 + q * 4 + r;
          partS[w * 32 + row] = s[mt][r];
          partQ[w * 32 + row] = sq[mt][r];
        }
    }
  }
  __syncthreads();
  // LN1 from registers -> h1n (bf16)
  {
    float lw[4], lb[4];
#pragma unroll
    for (int nt = 0; nt < 4; ++nt) {
      int col = w * 64 + nt * 16 + l15;
      lw[nt] = ln1w[col]; lb[nt] = ln1b[col];
    }
#pragma unroll
    for (int mt = 0; mt < 2; ++mt)
#pragma unroll
      for (int r = 0; r < 4; ++r) {
        int row = mt * 16 + q * 4 + r;
        float S = partS[row] + partS[32 + row] + partS[64 + row] + partS[96 + row];
        float Q = partQ[row] + partQ[32 + row] + partQ[64 + row] + partQ[96 + row];
        float mu = S * (1.f / 256.f);
        float var = Q * (1.f / 256.f) - mu * mu;
        float rstd = rsqrtf(var + 1e-5f);
#pragma unroll
        for (int nt = 0; nt < 4; ++nt) {
          int col = w * 64 + nt * 16 + l15;
          h1n[row * 264 + col] = f2b((acc[mt][nt][r] - mu) * rstd * lw[nt] + lb[nt]);
        }
      }
  }
  __syncthreads();
  // ---- GEMM2: [32,256] @ [256,128] ----
  f4_t acc2[2][2];
#pragma unroll
  for (int mt = 0; mt < 2; ++mt)
#pragma unroll
    for (int nt = 0; nt < 2; ++nt) acc2[mt][nt] = (f4_t){0.f, 0.f, 0.f, 0.f};
#pragma unroll
  for (int kst = 0; kst < 8; ++kst) {
    int k0 = kst * 32 + q * 8;
    bf8_t a0 = ldv(h1n + (l15) * 264 + k0);
    bf8_t a1 = ldv(h1n + (16 + l15) * 264 + k0);
#pragma unroll
    for (int nt = 0; nt < 2; ++nt) {
      int n = w * 32 + nt * 16 + l15;
      bf8_t b = ldv(w2t + n * 256 + k0);
      acc2[0][nt] = mfma16(a0, b, acc2[0][nt]);
      acc2[1][nt] = mfma16(a1, b, acc2[1][nt]);
    }
  }
  // bias in regs, partial sums
#pragma unroll
  for (int nt = 0; nt < 2; ++nt) {
    float bb = b2[w * 32 + nt * 16 + l15];
#pragma unroll
    for (int mt = 0; mt < 2; ++mt)
#pragma unroll
      for (int r = 0; r < 4; ++r)
        acc2[mt][nt][r] += bb;
  }
  {
    float s[2][4], sq[2][4];
#pragma unroll
    for (int mt = 0; mt < 2; ++mt)
#pragma unroll
      for (int r = 0; r < 4; ++r) {
        float a = acc2[mt][0][r], b = acc2[mt][1][r];
        s[mt][r] = a + b;
        sq[mt][r] = a * a + b * b;
      }
#pragma unroll
    for (int o = 1; o < 16; o <<= 1)
#pragma unroll
      for (int mt = 0; mt < 2; ++mt)
#pragma unroll
        for (int r = 0; r < 4; ++r) {
          s[mt][r] += __shfl_xor(s[mt][r], o);
          sq[mt][r] += __shfl_xor(sq[mt][r], o);
        }
    __syncthreads();  // all GEMM2 h1n reads done; partS/Q reads long done
    if (l15 == 0) {
#pragma unroll
      for (int mt = 0; mt < 2; ++mt)
#pragma unroll
        for (int r = 0; r < 4; ++r) {
          int row = mt * 16 + q * 4 + r;
          partS[w * 32 + row] = s[mt][r];
          partQ[w * 32 + row] = sq[mt][r];
        }
    }
  }
  __syncthreads();
  // LN2 + relu + clip -> h2n (bf16, aliased on h1n; safe after sync)
  {
    float lw[2], lb[2];
#pragma unroll
    for (int nt = 0; nt < 2; ++nt) {
      int col = w * 32 + nt * 16 + l15;
      lw[nt] = pnw[col]; lb[nt] = pnb[col];
    }
#pragma unroll
    for (int mt = 0; mt < 2; ++mt)
#pragma unroll
      for (int r = 0; r < 4; ++r) {
        int row = mt * 16 + q * 4 + r;
        float S = partS[row] + partS[32 + row] + partS[64 + row] + partS[96 + row];
        float Q = partQ[row] + partQ[32 + row] + partQ[64 + row] + partQ[96 + row];
        float mu = S * (1.f / 128.f);
        float var = Q * (1.f / 128.f) - mu * mu;
        float rstd = rsqrtf(var + 1e-5f);
#pragma unroll
        for (int nt = 0; nt < 2; ++nt) {
          int col = w * 32 + nt * 16 + l15;
          float v = (acc2[mt][nt][r] - mu) * rstd * lw[nt] + lb[nt];
          v = fminf(fmaxf(v, 0.f), 10.f);
          h2n[row * 128 + col] = f2b(v);
        }
      }
  }
  __syncthreads();
  // coalesced 32B stores
  {
    const int row = t >> 3, cb = (t & 7) * 16;
    int rg = rowbase + row;
    if (rg < NN) {
      uint4 v0 = *(const uint4*)(h2n + row * 128 + cb);
      uint4 v1 = *(const uint4*)(h2n + row * 128 + cb + 8);
      *(uint4*)(h16 + rg * 128 + cb) = v0;
      *(uint4*)(h16 + rg * 128 + cb + 8) = v1;
    }
  }
}

__global__ __launch_bounds__(256) void fillip_k(
    const int* srcv, const int* dstv, const float* etime, const float* tbl,
    const int* indptr, int* cursor, u16* recs,
    const float* x, const u16* w1t, const float* b1, const float* ln1w,
    const float* ln1b, const u16* w2t, const float* b2, const float* pnw,
    const float* pnb, u16* h16) {
  __shared__ char smem[17920];
  const int bid = blockIdx.x;
  if (bid % 3 == 0) {
    ip_body(bid / 3, smem, x, w1t, b1, ln1w, ln1b, w2t, b2, pnw, pnb, h16);
  } else {
    fill_body(bid - bid / 3 - 1, srcv, dstv, etime, tbl, indptr, cursor, recs);
  }
}

// ---------- MFMA node projection + attention logits ----------
__global__ __launch_bounds__(256) void hp_mfma(
    const u16* __restrict__ feat16, const u16* __restrict__ wt,
    const float* __restrict__ attsrc, const float* __restrict__ attdst,
    u16* __restrict__ hp16, float* __restrict__ asrc, float* __restrict__ adst) {
  const int t = threadIdx.x;
  const int w = t >> 6, lane = t & 63, q = lane >> 4, l15 = lane & 15;
  const int rowbase = blockIdx.x * 32;
  f4_t acc[2][2];
#pragma unroll
  for (int mt = 0; mt < 2; ++mt)
#pragma unroll
    for (int nt = 0; nt < 2; ++nt) acc[mt][nt] = (f4_t){0.f, 0.f, 0.f, 0.f};
#pragma unroll
  for (int kst = 0; kst < 4; ++kst) {
    int k0 = kst * 32 + q * 8;
    int r0 = rowbase + l15;      if (r0 > NN - 1) r0 = NN - 1;
    int r1 = rowbase + 16 + l15; if (r1 > NN - 1) r1 = NN - 1;
    bf8_t a0 = ldv(feat16 + r0 * 128 + k0);
    bf8_t a1 = ldv(feat16 + r1 * 128 + k0);
#pragma unroll
    for (int nt = 0; nt < 2; ++nt) {
      int n = w * 32 + nt * 16 + l15;
      bf8_t b = ldv(wt + n * 128 + k0);
      acc[0][nt] = mfma16(a0, b, acc[0][nt]);
      acc[1][nt] = mfma16(a1, b, acc[1][nt]);
    }
  }
  float ps[2][4], pd[2][4];
#pragma unroll
  for (int mt = 0; mt < 2; ++mt)
#pragma unroll
    for (int r = 0; r < 4; ++r) { ps[mt][r] = 0.f; pd[mt][r] = 0.f; }
#pragma unroll
  for (int mt = 0; mt < 2; ++mt)
#pragma unroll
    for (int nt = 0; nt < 2; ++nt) {
      int col = w * 32 + nt * 16 + l15;
      float as = attsrc[col], ad = attdst[col];
#pragma unroll
      for (int r = 0; r < 4; ++r) {
        int row = mt * 16 + q * 4 + r;
        int rg = rowbase + row;
        float v = acc[mt][nt][r];
        if (rg < NN) hp16[(size_t)rg * 128 + col] = f2b(v);
        ps[mt][r] += v * as;
        pd[mt][r] += v * ad;
      }
    }
#pragma unroll
  for (int o = 1; o < 16; o <<= 1)
#pragma unroll
    for (int mt = 0; mt < 2; ++mt)
#pragma unroll
      for (int r = 0; r < 4; ++r) {
        ps[mt][r] += __shfl_xor(ps[mt][r], o);
        pd[mt][r] += __shfl_xor(pd[mt][r], o);
      }
  if (l15 == 0) {
#pragma unroll
    for (int mt = 0; mt < 2; ++mt)
#pragma unroll
      for (int r = 0; r < 4; ++r) {
        int rg = rowbase + mt * 16 + q * 4 + r;
        if (rg < NN) {
          asrc[rg * 4 + w] = ps[mt][r];
          adst[rg * 4 + w] = pd[mt][r];
        }
      }
  }
}

// ---------- GAT aggregation: single pass, 16-lane x 8-ch layout ----------
template <int L, int FINAL>
__global__ __launch_bounds__(256) void agg_k(
    const int* __restrict__ indptr, const u16* __restrict__ recs,
    const float* __restrict__ asrc, const float* __restrict__ adst,
    const u16* __restrict__ hp16, const u16* __restrict__ feat16,
    const float* __restrict__ gbias, const float* __restrict__ lnw,
    const float* __restrict__ lnb, u16* __restrict__ gout16,
    float* __restrict__ out32) {
  const int wv = threadIdx.x >> 6, lane = threadIdx.x & 63;
  const int n = blockIdx.x * 4 + wv;
  if (n >= NN) return;
  const int s0 = indptr[n], s1 = indptr[n + 1];
  const int dg = s1 - s0;
  const int g = lane >> 4, sl = lane & 15, cb = sl * 8, hdB = sl >> 2;
  const float advB = adst[n * 4 + hdB];
  float ssp = 0.f, sap = 0.f;
  float acc[8];
#pragma unroll
  for (int i = 0; i < 8; ++i) acc[i] = 0.f;
  for (int base = s0; base < s1; base += 8) {
    int i0 = base + g, i1 = base + 4 + g;
    int j0 = i0 < s1 ? i0 : s1 - 1;
    int j1 = i1 < s1 ? i1 : s1 - 1;
    const u16* r0 = recs + (size_t)j0 * 16;
    const u16* r1 = recs + (size_t)j1 * 16;
    int sc0 = *(const int*)r0, sc1 = *(const int*)r1;
    float ae0 = h2f(r0[2 + 4 * L + hdB]);
    float ae1v = h2f(r1[2 + 4 * L + hdB]);
    float as0 = asrc[sc0 * 4 + hdB], as1 = asrc[sc1 * 4 + hdB];
    const uint4 row0 = *(const uint4*)(hp16 + (size_t)sc0 * 128 + cb);
    const uint4 row1 = *(const uint4*)(hp16 + (size_t)sc1 * 128 + cb);
    float l0 = as0 + advB + ae0; l0 = fmaxf(l0, 0.2f * l0);
    float l1 = as1 + advB + ae1v; l1 = fmaxf(l1, 0.2f * l1);
    float w0 = (i0 < s1) ? __expf(l0) : 0.f;
    float w1 = (i1 < s1) ? __expf(l1) : 0.f;
    ssp += w0 + w1;
    sap += ((i0 < s1) ? ae0 : 0.f) + ((i1 < s1) ? ae1v : 0.f);
    acc[0] += w0 * blo(row0.x) + w1 * blo(row1.x);
    acc[1] += w0 * bhi(row0.x) + w1 * bhi(row1.x);
    acc[2] += w0 * blo(row0.y) + w1 * blo(row1.y);
    acc[3] += w0 * bhi(row0.y) + w1 * bhi(row1.y);
    acc[4] += w0 * blo(row0.z) + w1 * blo(row1.z);
    acc[5] += w0 * bhi(row0.z) + w1 * bhi(row1.z);
    acc[6] += w0 * blo(row0.w) + w1 * blo(row1.w);
    acc[7] += w0 * bhi(row0.w) + w1 * bhi(row1.w);
  }
  // reduce across the 4 edge-groups
#pragma unroll
  for (int i = 0; i < 8; ++i) {
    acc[i] += __shfl_xor(acc[i], 16);
    acc[i] += __shfl_xor(acc[i], 32);
  }
  ssp += __shfl_xor(ssp, 16); ssp += __shfl_xor(ssp, 32);
  sap += __shfl_xor(sap, 16); sap += __shfl_xor(sap, 32);
  // self-loop (fill_value='mean' fold) + normalization
  const float degf = (float)(dg > 0 ? dg : 1);
  float asnB = asrc[n * 4 + hdB];
  float la = asnB + advB + sap / degf;
  la = fmaxf(la, 0.2f * la);
  float wsf = __expf(la);
  float inv = 1.f / (ssp + wsf + 1e-16f);
  // epilogue
  const uint4 rs4 = *(const uint4*)(hp16 + (size_t)n * 128 + cb);
  const uint4 rr4 = *(const uint4*)(feat16 + (size_t)n * 128 + cb);
  const float4 gb0 = *(const float4*)(gbias + cb);
  const float4 gb1 = *(const float4*)(gbias + cb + 4);
  float v[8];
  v[0] = (acc[0] + wsf * blo(rs4.x)) * inv + gb0.x + blo(rr4.x);
  v[1] = (acc[1] + wsf * bhi(rs4.x)) * inv + gb0.y + bhi(rr4.x);
  v[2] = (acc[2] + wsf * blo(rs4.y)) * inv + gb0.z + blo(rr4.y);
  v[3] = (acc[3] + wsf * bhi(rs4.y)) * inv + gb0.w + bhi(rr4.y);
  v[4] = (acc[4] + wsf * blo(rs4.z)) * inv + gb1.x + blo(rr4.z);
  v[5] = (acc[5] + wsf * bhi(rs4.z)) * inv + gb1.y + bhi(rr4.z);
  v[6] = (acc[6] + wsf * blo(rs4.w)) * inv + gb1.z + blo(rr4.w);
  v[7] = (acc[7] + wsf * bhi(rs4.w)) * inv + gb1.w + bhi(rr4.w);
  float sum = 0.f, sq = 0.f;
#pragma unroll
  for (int i = 0; i < 8; ++i) {
    v[i] = fminf(fmaxf(v[i], -10.f), 10.f);
    sum += v[i]; sq += v[i] * v[i];
  }
#pragma unroll
  for (int o = 1; o < 16; o <<= 1) {
    sum += __shfl_xor(sum, o);
    sq += __shfl_xor(sq, o);
  }
  float mu = sum * (1.f / 128.f);
  float var = sq * (1.f / 128.f) - mu * mu;
  float rstd = rsqrtf(var + 1e-5f);
  const float4 lw0 = *(const float4*)(lnw + cb);
  const float4 lw1 = *(const float4*)(lnw + cb + 4);
  const float4 lb0 = *(const float4*)(lnb + cb);
  const float4 lb1 = *(const float4*)(lnb + cb + 4);
  float y[8];
  y[0] = (v[0] - mu) * rstd * lw0.x + lb0.x;
  y[1] = (v[1] - mu) * rstd * lw0.y + lb0.y;
  y[2] = (v[2] - mu) * rstd * lw0.z + lb0.z;
  y[3] = (v[3] - mu) * rstd * lw0.w + lb0.w;
  y[4] = (v[4] - mu) * rstd * lw1.x + lb1.x;
  y[5] = (v[5] - mu) * rstd * lw1.y + lb1.y;
  y[6] = (v[6] - mu) * rstd * lw1.z + lb1.z;
  y[7] = (v[7] - mu) * rstd * lw1.w + lb1.w;
#pragma unroll
  for (int i = 0; i < 8; ++i) y[i] = y[i] > 0.f ? y[i] : expm1f(y[i]);
  if (g == 0) {
    if (FINAL) {
      float4 o0 = {y[0], y[1], y[2], y[3]};
      float4 o1 = {y[4], y[5], y[6], y[7]};
      *(float4*)(out32 + (size_t)n * 128 + cb) = o0;
      *(float4*)(out32 + (size_t)n * 128 + cb + 4) = o1;
    } else {
      uint4 o;
      o.x = (unsigned)f2b(y[0]) | ((unsigned)f2b(y[1]) << 16);
      o.y = (unsigned)f2b(y[2]) | ((unsigned)f2b(y[3]) << 16);
      o.z = (unsigned)f2b(y[4]) | ((unsigned)f2b(y[5]) << 16);
      o.w = (unsigned)f2b(y[6]) | ((unsigned)f2b(y[7]) << 16);
      *(uint4*)(gout16 + (size_t)n * 128 + cb) = o;
    }
  }
}

// ---------- launch ----------
extern "C" void kernel_launch(void* const* d_in, const int* in_sizes, int n_in,
                              void* d_out, int out_size, void* d_ws, size_t ws_size,
                              hipStream_t stream) {
  const float* x      = (const float*)d_in[0];
  const float* etime  = (const float*)d_in[1];
  const float* ip_w1  = (const float*)d_in[2];
  const float* ip_b1  = (const float*)d_in[3];
  const float* ip_lnw = (const float*)d_in[4];
  const float* ip_lnb = (const float*)d_in[5];
  const float* ip_w2  = (const float*)d_in[6];
  const float* ip_b2  = (const float*)d_in[7];
  const float* pn_w   = (const float*)d_in[8];
  const float* pn_b   = (const float*)d_in[9];
  const float* ta_w1  = (const float*)d_in[10];
  const float* ta_b1  = (const float*)d_in[11];
  const float* ta_lnw = (const float*)d_in[12];
  const float* ta_lnb = (const float*)d_in[13];
  const float* ta_w2  = (const float*)d_in[14];
  const float* ta_b2  = (const float*)d_in[15];
  const float* g1_w   = (const float*)d_in[16];
  const float* g1_as  = (const float*)d_in[17];
  const float* g1_ad  = (const float*)d_in[18];
  const float* g1_ew  = (const float*)d_in[19];
  const float* g1_ae  = (const float*)d_in[20];
  const float* g1_b   = (const float*)d_in[21];
  const float* g2_w   = (const float*)d_in[22];
  const float* g2_as  = (const float*)d_in[23];
  const float* g2_ad  = (const float*)d_in[24];
  const float* g2_ew  = (const float*)d_in[25];
  const float* g2_ae  = (const float*)d_in[26];
  const float* g2_b   = (const float*)d_in[27];
  const float* n1_w   = (const float*)d_in[28];
  const float* n1_b   = (const float*)d_in[29];
  const float* n2_w   = (const float*)d_in[30];
  const float* n2_b   = (const float*)d_in[31];
  const int* eidx     = (const int*)d_in[32];
  const int* srcv = eidx;
  const int* dstv = eidx + NE;

  char* p = (char*)d_ws;
  auto carve = [&](size_t bytes) -> char* {
    char* r = p;
    p += (bytes + 255) & ~(size_t)255;
    return r;
  };
  u16*   h16    = (u16*)carve((size_t)NN * 128 * 2);
  u16*   g16    = (u16*)carve((size_t)NN * 128 * 2);
  u16*   hp16   = (u16*)carve((size_t)NN * 128 * 2);
  float* asrc   = (float*)carve((size_t)NN * 4 * 4);
  float* adst   = (float*)carve((size_t)NN * 4 * 4);
  u16*   recs   = (u16*)carve((size_t)NE * 32);
  int*   deg    = (int*)carve((size_t)NN * 4);
  int*   indptr = (int*)carve((size_t)(NN + 1) * 4);
  int*   cursor = (int*)carve((size_t)NN * 4);
  int*   blks   = (int*)carve(512 * 4);
  float* V      = (float*)carve(128 * 8 * 4);
  float* tbl    = (float*)carve((size_t)TBLN * 8 * 4);
  u16*   w1t    = (u16*)carve(128 * 256 * 2);
  u16*   w2t    = (u16*)carve(256 * 128 * 2);
  u16*   g1wt   = (u16*)carve(128 * 128 * 2);
  u16*   g2wt   = (u16*)carve(128 * 128 * 2);

  hipMemsetAsync(deg, 0, (size_t)NN * 4, stream);
  hipMemsetAsync(cursor, 0, (size_t)NN * 4, stream);

  const int SCB = (NN + 511) / 512;  // 98

  prep_k<<<1 + 384 + FB, 256, 0, stream>>>(g1_ew, g1_ae, g2_ew, g2_ae, V,
                                           ip_w1, ip_w2, g1_w, g2_w,
                                           w1t, w2t, g1wt, g2wt, dstv, deg);
  build_table<<<TBLN, 128, 0, stream>>>(ta_w1, ta_b1, ta_lnw, ta_lnb, ta_w2, ta_b2, V, tbl);
  scan1<<<SCB, 512, 0, stream>>>(deg, indptr, blks);
  scan2<<<1, 128, 0, stream>>>(blks, SCB);
  scan3<<<SCB, 512, 0, stream>>>(indptr, blks);
  fillip_k<<<MB + FB, 256, 0, stream>>>(srcv, dstv, etime, tbl, indptr, cursor, recs,
                                        x, w1t, ip_b1, ip_lnw, ip_lnb, w2t, ip_b2,
                                        pn_w, pn_b, h16);
  hp_mfma<<<MB, 256, 0, stream>>>(h16, g1wt, g1_as, g1_ad, hp16, asrc, adst);
  agg_k<0, 0><<<NN / 4, 256, 0, stream>>>(indptr, recs, asrc, adst, hp16, h16,
                                          g1_b, n1_w, n1_b, g16, nullptr);
  hp_mfma<<<MB, 256, 0, stream>>>(g16, g2wt, g2_as, g2_ad, hp16, asrc, adst);
  agg_k<1, 1><<<NN / 4, 256, 0, stream>>>(indptr, recs, asrc, adst, hp16, g16,
                                          g2_b, n2_w, n2_b, nullptr, (float*)d_out);
}